// Round 1
// baseline (342.222 us; speedup 1.0000x reference)
//
#include <hip/hip_runtime.h>

#define D 128
#define KOUT 100
#define CHUNK 4096   // edges per pass-1 block

typedef __attribute__((ext_vector_type(8))) short short8;
typedef __attribute__((ext_vector_type(4))) float floatx4;

// ---------------- bf16 pack/unpack helpers ----------------
__device__ inline float bf_lo(unsigned int u) { return __uint_as_float(u << 16); }
__device__ inline float bf_hi(unsigned int u) { return __uint_as_float(u & 0xFFFF0000u); }

__device__ inline unsigned int bf_round(float a) {      // f32 -> bf16 bits (RNE)
    unsigned int ua = __float_as_uint(a);
    return (ua + 0x7FFFu + ((ua >> 16) & 1u)) >> 16;
}
__device__ inline unsigned int pack_bf(float a, float b) {
    return bf_round(a) | (bf_round(b) << 16);
}

// ---------------- CSR build pass 1: bucket radix partition ----------------
// bucket = dst >> 8; packed record: bits[23:0]=src, bits[31:24]=dst&255

__launch_bounds__(256)
__global__ void bucket_pass1(const int* __restrict__ ei, int E, int nbuck, int cap,
                             int* __restrict__ bcur, unsigned int* __restrict__ bdata) {
    __shared__ int hist[256];
    __shared__ int sc[256];
    __shared__ int pfx[256];
    __shared__ int cur[256];
    __shared__ int gbase[256];
    __shared__ unsigned int lbuf[CHUNK];      // 16 KB
    __shared__ unsigned char bkt[CHUNK];      // 4 KB

    int tid = threadIdx.x;
    int base = blockIdx.x * CHUNK;
    int cnt = E - base; if (cnt > CHUNK) cnt = CHUNK;

    hist[tid] = 0;
    __syncthreads();

    int src[CHUNK / 256];
    int dst[CHUNK / 256];
#pragma unroll
    for (int q = 0; q < CHUNK / 256; q++) {
        int li = tid + q * 256;
        if (li < cnt) {
            src[q] = ei[base + li];
            dst[q] = ei[E + base + li];
            atomicAdd(&hist[dst[q] >> 8], 1);
        }
    }
    __syncthreads();

    int v = hist[tid];
    sc[tid] = v;
    __syncthreads();
    for (int off = 1; off < 256; off <<= 1) {
        int t = (tid >= off) ? sc[tid - off] : 0;
        __syncthreads();
        sc[tid] += t;
        __syncthreads();
    }
    int excl = sc[tid] - v;
    pfx[tid] = excl;
    cur[tid] = excl;
    gbase[tid] = 0;
    if (tid < nbuck && v > 0) gbase[tid] = atomicAdd(&bcur[tid], v);
    __syncthreads();

#pragma unroll
    for (int q = 0; q < CHUNK / 256; q++) {
        int li = tid + q * 256;
        if (li < cnt) {
            int b = dst[q] >> 8;
            int p = atomicAdd(&cur[b], 1);
            lbuf[p] = (unsigned int)src[q] | ((unsigned int)(dst[q] & 255) << 24);
            bkt[p] = (unsigned char)b;
        }
    }
    __syncthreads();

    for (int p = tid; p < cnt; p += 256) {
        int b = bkt[p];
        bdata[(size_t)b * cap + gbase[b] + (p - pfx[b])] = lbuf[p];
    }
}

// ---------------- CSR build pass 2 (fused): dinv + rowptr + scatter ----------------
// one block per bucket; bdata read twice (2nd read L2-hot).

__launch_bounds__(256)
__global__ void bucket_build(const unsigned int* __restrict__ bdata, const int* __restrict__ bcur,
                             int cap, float* __restrict__ dinv,
                             int* __restrict__ rowptr, int* __restrict__ csr, int n, int nbuck) {
    __shared__ int cnts[256];
    __shared__ int sc[256];
    __shared__ int cur[256];
    __shared__ int bbase;

    int b = blockIdx.x, tid = threadIdx.x;
    if (tid == 0) bbase = 0;
    cnts[tid] = 0;
    __syncthreads();

    // sum of bucket counts before b
    int part = 0;
    for (int t = tid; t < b; t += 256) part += bcur[t];
#pragma unroll
    for (int off = 32; off > 0; off >>= 1) part += __shfl_down(part, off);
    if ((tid & 63) == 0 && part != 0) atomicAdd(&bbase, part);

    int cnt = bcur[b];
    const unsigned int* p = bdata + (size_t)b * cap;
    for (int e = tid; e < cnt; e += 256) atomicAdd(&cnts[p[e] >> 24], 1);
    __syncthreads();

    int v = cnts[tid];
    sc[tid] = v;
    __syncthreads();
    for (int off = 1; off < 256; off <<= 1) {
        int t = (tid >= off) ? sc[tid - off] : 0;
        __syncthreads();
        sc[tid] += t;
        __syncthreads();
    }
    int gstart = bbase + (sc[tid] - v);
    int node = b * 256 + tid;
    if (node < n) {
        dinv[node] = rsqrtf((float)(v + 1));
        rowptr[node] = gstart;
    }
    cur[tid] = gstart;
    __syncthreads();

    for (int e = tid; e < cnt; e += 256) {
        unsigned int u = p[e];
        int pos = atomicAdd(&cur[u >> 24], 1);
        csr[pos] = (int)(u & 0xFFFFFFu);
    }
}

// ---------------- Weight prep + bcur zero + Hb zero-rows + rowptr sentinel ----------------
// Wfrag[(kt*8+ct)*64 + lane][j] = W[kt*32 + (lane>>4)*8 + j][ct*16 + (lane&15)]
// H tables are chunk-major: [4 chunks][(N+1) rows][16 uint (=32 bf16 feats)]

__global__ void prep_frag_kernel(const float* __restrict__ W1, const float* __restrict__ W2,
                                 const float* __restrict__ Wa, const float* __restrict__ ba,
                                 unsigned short* __restrict__ Wf1, unsigned short* __restrict__ Wf2,
                                 unsigned short* __restrict__ WfA, float* __restrict__ bpad,
                                 int* __restrict__ bcur, int* __restrict__ rowptr,
                                 unsigned int* __restrict__ HbA, unsigned int* __restrict__ HbB,
                                 int n, int E) {
    int idx = blockIdx.x * blockDim.x + threadIdx.x;
    if (idx < 3 * 16384) {
        int m = idx / 16384;
        int e = idx & 16383;
        int j = e & 7, lane = (e >> 3) & 63, ct = (e >> 9) & 7, kt = e >> 12;
        int k = kt * 32 + (lane >> 4) * 8 + j;
        int col = ct * 16 + (lane & 15);
        float val;
        unsigned short* dst;
        if (m == 0)      { val = W1[k * 128 + col]; dst = Wf1; }
        else if (m == 1) { val = W2[k * 128 + col]; dst = Wf2; }
        else             { val = (col < KOUT) ? Wa[k * KOUT + col] : 0.f; dst = WfA; }
        dst[e] = (unsigned short)bf_round(val);
    }
    if (idx < 128) bpad[idx] = (idx < KOUT) ? ba[idx] : 0.f;
    if (idx < 256) bcur[idx] = 0;
    if (idx < 64) {   // zero row (node index n) in each of the 4 chunk tables
        int ch = idx >> 4, cc = idx & 15;
        size_t zoff = ((size_t)ch * (n + 1) + n) * 16 + cc;
        HbA[zoff] = 0u;
        HbB[zoff] = 0u;
    }
    if (idx == 256) rowptr[n] = E;   // sentinel
}

// ---------------- MFMA GEMM ----------------
// block 256 = 4 waves; tile 64 rows x 128 cols; wave w: rows w*16..+15.
// in_bf16: A-fragments read directly from chunk-major bf16 tables
//          (chunk kt holds feats kt*32..+32, so a short8 stays contiguous).
// out_mode 1: chunk-major bf16 rows, each row scaled by oscale[row] if given.
// out_mode 2: +bias, softmax over first KOUT cols, f32 [nrows, KOUT] output.

__launch_bounds__(256)
__global__ void gemm_mfma_kernel(const void* __restrict__ Xin, const unsigned short* __restrict__ Wf,
                                 const float* __restrict__ bias, const float* __restrict__ oscale,
                                 void* __restrict__ Y, int nrows, int in_bf16, int out_mode) {
    __shared__ float lds_f[64 * 130];                      // 33280 B
    unsigned short* lds_h = (unsigned short*)lds_f;
    unsigned int* lds_u = (unsigned int*)lds_f;

    int tid = threadIdx.x;
    int w = tid >> 6, lane = tid & 63;
    int quad = lane >> 4, m16 = lane & 15;
    int r0 = blockIdx.x * 64;
    unsigned tstride = (unsigned)(nrows + 1) * 16u;        // uints per chunk table

    if (!in_bf16) {
        int row = tid >> 2, cg_ = tid & 3;
        bool valid = (r0 + row) < nrows;
        const float4* Xr = (const float4*)Xin + (size_t)(r0 + row) * 32 + cg_ * 8;
#pragma unroll
        for (int j = 0; j < 8; j++) {
            float4 v = valid ? Xr[j] : make_float4(0.f, 0.f, 0.f, 0.f);
            int c = cg_ * 32 + j * 4;
            lds_u[row * 68 + (c >> 1)]     = pack_bf(v.x, v.y);
            lds_u[row * 68 + (c >> 1) + 1] = pack_bf(v.z, v.w);
        }
        __syncthreads();
    }

    floatx4 acc[8];
#pragma unroll
    for (int ct = 0; ct < 8; ct++) acc[ct] = (floatx4){0.f, 0.f, 0.f, 0.f};

    int arow = r0 + w * 16 + m16;
    if (arow > nrows - 1) arow = nrows - 1;
    const unsigned int* Xb = (const unsigned int*)Xin;

    const short8* Wf8 = (const short8*)Wf;
#pragma unroll
    for (int kt = 0; kt < 4; kt++) {
        short8 a;
        if (in_bf16) {
            a = *(const short8*)(Xb + (unsigned)kt * tstride + (unsigned)arow * 16u + (unsigned)(quad * 4));
        } else {
            a = *(const short8*)(lds_h + (w * 16 + m16) * 136 + kt * 32 + quad * 8);
        }
#pragma unroll
        for (int ct = 0; ct < 8; ct++) {
            short8 b = Wf8[(kt * 8 + ct) * 64 + lane];
            acc[ct] = __builtin_amdgcn_mfma_f32_16x16x32_bf16(a, b, acc[ct], 0, 0, 0);
        }
    }

    if (out_mode == 1) {
        __syncthreads();   // reuse LDS as f32 out staging [64][130]
#pragma unroll
        for (int ct = 0; ct < 8; ct++) {
#pragma unroll
            for (int r = 0; r < 4; r++) {
                int rl = w * 16 + quad * 4 + r;
                lds_f[rl * 130 + ct * 16 + m16] = acc[ct][r];
            }
        }
        __syncthreads();
        unsigned int* Yb = (unsigned int*)Y;
        for (int r = 0; r < 16; r++) {
            int row = r0 + w * 16 + r;
            if (row < nrows) {
                float sc = oscale ? oscale[row] : 1.f;
                float lo = lds_f[(w * 16 + r) * 130 + 2 * lane] * sc;
                float hi = lds_f[(w * 16 + r) * 130 + 2 * lane + 1] * sc;
                // feature pair 2*lane,2*lane+1 -> chunk lane>>4, uint lane&15
                Yb[(size_t)(lane >> 4) * tstride + (unsigned)row * 16u + (unsigned)(lane & 15)] =
                    pack_bf(lo, hi);
            }
        }
    } else {
        // out_mode 2: bias + softmax over cols < KOUT, f32 output [nrows, KOUT]
        float bb[8];
#pragma unroll
        for (int ct = 0; ct < 8; ct++) bb[ct] = bias[ct * 16 + m16];
        float* Yf = (float*)Y;
#pragma unroll
        for (int r = 0; r < 4; r++) {
            int row = r0 + w * 16 + quad * 4 + r;
            float vv[8];
            float mx = -1e30f;
#pragma unroll
            for (int ct = 0; ct < 8; ct++) {
                int col = ct * 16 + m16;
                vv[ct] = (col < KOUT) ? acc[ct][r] + bb[ct] : -1e30f;
                mx = fmaxf(mx, vv[ct]);
            }
#pragma unroll
            for (int off = 1; off < 16; off <<= 1) mx = fmaxf(mx, __shfl_xor(mx, off));
            float se = 0.f;
#pragma unroll
            for (int ct = 0; ct < 8; ct++) {
                vv[ct] = (vv[ct] > -1e29f) ? __expf(vv[ct] - mx) : 0.f;
                se += vv[ct];
            }
#pragma unroll
            for (int off = 1; off < 16; off <<= 1) se += __shfl_xor(se, off);
            float inv = 1.f / se;
            if (row < nrows) {
#pragma unroll
                for (int ct = 0; ct < 8; ct++) {
                    int col = ct * 16 + m16;
                    if (col < KOUT) Yf[(size_t)row * KOUT + col] = vv[ct] * inv;
                }
            }
        }
    }
}

// ---------------- Aggregate (feature-chunked, XCD-pinned) ----------------
// H tables chunk-major [4][(N+1)][16 uint]; chunk = blockIdx & 3 so on the
// 8-XCD round-robin block->XCD map, chunk c lives on XCDs {c, c+4} and its
// 3.2 MB table stays L2-resident. csr/output use nontemporal hints so the
// streams don't evict the table.
// wave = one (node, chunk): g=lane>>4 edge slot (x4 unroll), c=lane&15 uint.
// main loop bounds-free; tail masked to zero-row n. cnt/cp scalarized.

__launch_bounds__(256)
__global__ void aggregate_kernel(const unsigned int* __restrict__ Hb, const int* __restrict__ csr,
                                 const int* __restrict__ rowptr,
                                 const float* __restrict__ dinv, const float* __restrict__ bias,
                                 unsigned int* __restrict__ Ob, int n, int do_relu) {
    int wid = threadIdx.x >> 6, lane = threadIdx.x & 63;
    int chunk = blockIdx.x & 3;
    int i0 = (blockIdx.x >> 2) * 4 + wid;
    if (i0 >= n) return;
    int i = __builtin_amdgcn_readfirstlane(i0);
    int g = lane >> 4, c = lane & 15;

    unsigned tstride = (unsigned)(n + 1) * 16u;
    const unsigned int* T = Hb + (size_t)chunk * tstride;

    float di = dinv[i];
    int start = rowptr[i];
    int cnt = rowptr[i + 1] - start;
    const int* cp = csr + start;

    float aLo, aHi;
    {   // self term (slot 0 only); rows are dinv[src]-prescaled by the GEMM
        unsigned int su = (g == 0) ? T[(unsigned)i * 16u + c] : 0u;
        aLo = bf_lo(su);
        aHi = bf_hi(su);
    }

    int gb = g * 4;
    int s0 = (gb + 0 < cnt) ? __builtin_nontemporal_load(cp + gb + 0) : n;
    int s1 = (gb + 1 < cnt) ? __builtin_nontemporal_load(cp + gb + 1) : n;
    int s2 = (gb + 2 < cnt) ? __builtin_nontemporal_load(cp + gb + 2) : n;
    int s3 = (gb + 3 < cnt) ? __builtin_nontemporal_load(cp + gb + 3) : n;

    int e = 0;
    for (; e + 32 <= cnt; e += 16) {          // bounds-free main loop
        unsigned int v0 = T[(unsigned)s0 * 16u + c];
        unsigned int v1 = T[(unsigned)s1 * 16u + c];
        unsigned int v2 = T[(unsigned)s2 * 16u + c];
        unsigned int v3 = T[(unsigned)s3 * 16u + c];
        int t0 = __builtin_nontemporal_load(cp + e + 16 + gb + 0);
        int t1 = __builtin_nontemporal_load(cp + e + 16 + gb + 1);
        int t2 = __builtin_nontemporal_load(cp + e + 16 + gb + 2);
        int t3 = __builtin_nontemporal_load(cp + e + 16 + gb + 3);
        float l01 = bf_lo(v0) + bf_lo(v1);
        float l23 = bf_lo(v2) + bf_lo(v3);
        float h01 = bf_hi(v0) + bf_hi(v1);
        float h23 = bf_hi(v2) + bf_hi(v3);
        aLo += l01 + l23;
        aHi += h01 + h23;
        s0 = t0; s1 = t1; s2 = t2; s3 = t3;
    }
    for (; e < cnt; e += 16) {                // masked tail (<= 2 iters)
        unsigned int v0 = T[(unsigned)s0 * 16u + c];
        unsigned int v1 = T[(unsigned)s1 * 16u + c];
        unsigned int v2 = T[(unsigned)s2 * 16u + c];
        unsigned int v3 = T[(unsigned)s3 * 16u + c];
        int b0 = e + 16 + gb;
        int t0 = (b0 + 0 < cnt) ? __builtin_nontemporal_load(cp + b0 + 0) : n;
        int t1 = (b0 + 1 < cnt) ? __builtin_nontemporal_load(cp + b0 + 1) : n;
        int t2 = (b0 + 2 < cnt) ? __builtin_nontemporal_load(cp + b0 + 2) : n;
        int t3 = (b0 + 3 < cnt) ? __builtin_nontemporal_load(cp + b0 + 3) : n;
        float l01 = bf_lo(v0) + bf_lo(v1);
        float l23 = bf_lo(v2) + bf_lo(v3);
        float h01 = bf_hi(v0) + bf_hi(v1);
        float h23 = bf_hi(v2) + bf_hi(v3);
        aLo += l01 + l23;
        aHi += h01 + h23;
        s0 = t0; s1 = t1; s2 = t2; s3 = t3;
    }

    // reduce the 4 edge-slot groups (lane bits 4,5)
    aLo += __shfl_xor(aLo, 16); aLo += __shfl_xor(aLo, 32);
    aHi += __shfl_xor(aHi, 16); aHi += __shfl_xor(aHi, 32);

    if (g == 0) {
        float2 bb = ((const float2*)bias)[chunk * 16 + c];
        float fx = aLo * di + bb.x;
        float fy = aHi * di + bb.y;
        if (do_relu) { fx = fmaxf(fx, 0.f); fy = fmaxf(fy, 0.f); }
        __builtin_nontemporal_store(pack_bf(fx, fy),
                                    &Ob[(size_t)chunk * tstride + (unsigned)i * 16u + c]);
    }
}

// ---------------- launch ----------------

extern "C" void kernel_launch(void* const* d_in, const int* in_sizes, int n_in,
                              void* d_out, int out_size, void* d_ws, size_t ws_size,
                              hipStream_t stream) {
    const float* x  = (const float*)d_in[0];
    const int*   ei = (const int*)d_in[1];     // [2,E] int32
    const float* W1 = (const float*)d_in[2];
    const float* b1 = (const float*)d_in[3];
    const float* W2 = (const float*)d_in[4];
    const float* b2 = (const float*)d_in[5];
    const float* Wa = (const float*)d_in[6];
    const float* ba = (const float*)d_in[7];
    float* out = (float*)d_out;

    int N = in_sizes[0] / D;
    int E = in_sizes[1] / 2;

    int nbuck = (N + 255) >> 8;                       // 196 for N=50000
    int cap = ((E / nbuck) + 2048 + 63) & ~63;

    char* w = (char*)d_ws;
    size_t off = 0;
    auto carve = [&](size_t bytes) -> void* {
        void* p = w + off;
        off = (off + bytes + 255) & ~(size_t)255;
        return p;
    };
    float* dinv   = (float*)carve((size_t)N * 4);
    int*   rowptr = (int*)carve((size_t)(N + 1) * 4);
    int*   bcur   = (int*)carve(256 * 4);
    unsigned int* bdata = (unsigned int*)carve((size_t)nbuck * cap * 4);
    int*   csr    = (int*)carve((size_t)E * 4);
    unsigned short* Wf1 = (unsigned short*)carve(16384 * 2);
    unsigned short* Wf2 = (unsigned short*)carve(16384 * 2);
    unsigned short* WfA = (unsigned short*)carve(16384 * 2);
    float* bpad   = (float*)carve(512);
    unsigned int* HbA = (unsigned int*)carve((size_t)(N + 1) * 64 * 4);  // 4 chunks x (N+1) x 16 uint
    unsigned int* HbB = (unsigned int*)carve((size_t)(N + 1) * 64 * 4);
    (void)ws_size; (void)n_in; (void)out_size;

    int nbNode4 = (N + 3) / 4;
    int nbGemm = (N + 63) / 64;
    int nbP1 = (E + CHUNK - 1) / CHUNK;

    prep_frag_kernel<<<192, 256, 0, stream>>>(W1, W2, Wa, ba, Wf1, Wf2, WfA, bpad,
                                              bcur, rowptr, HbA, HbB, N, E);
    bucket_pass1<<<nbP1, 256, 0, stream>>>(ei, E, nbuck, cap, bcur, bdata);
    bucket_build<<<nbuck, 256, 0, stream>>>(bdata, bcur, cap, dinv, rowptr, csr, N, nbuck);

    // layer 1 (gemm writes chunk-major bf16(h*dinv) rows)
    gemm_mfma_kernel<<<nbGemm, 256, 0, stream>>>(x, Wf1, nullptr, dinv, HbA, N, 0, 1);
    aggregate_kernel<<<nbNode4 * 4, 256, 0, stream>>>(HbA, csr, rowptr, dinv, b1, HbB, N, 1);
    // layer 2
    gemm_mfma_kernel<<<nbGemm, 256, 0, stream>>>(HbB, Wf2, nullptr, dinv, HbA, N, 1, 1);
    aggregate_kernel<<<nbNode4 * 4, 256, 0, stream>>>(HbA, csr, rowptr, dinv, b2, HbB, N, 0);
    // attention + fused softmax -> out
    gemm_mfma_kernel<<<nbGemm, 256, 0, stream>>>(HbB, WfA, bpad, nullptr, out, N, 1, 2);
}